// Round 2
// baseline (403.231 us; speedup 1.0000x reference)
//
#include <hip/hip_runtime.h>
#include <hip/hip_bf16.h>

typedef __attribute__((ext_vector_type(8))) short short8;
typedef __attribute__((ext_vector_type(4))) float float4v;

#define NSAMP 10000
#define CIN   64
#define TLEN  64
#define COUT  64     // channels after GLU
#define TOUT  62

// fp32 -> bf16 bits, round-to-nearest-even (inputs are never NaN/Inf)
static __device__ __forceinline__ ushort f2bf(float v) {
    unsigned int x = __float_as_uint(v);
    return (ushort)((x + 0x7fffu + ((x >> 16) & 1u)) >> 16);
}

// Pre-permute + downconvert weights: Wa[co][kk], kk = k*64 + ci (bf16 bits).
// src: float w[co][ci][k] (strides 192, 3, 1)
__global__ void prep_weights(const float* __restrict__ w, ushort* __restrict__ wa) {
    int o = blockIdx.x * blockDim.x + threadIdx.x;
    if (o >= 128 * 192) return;
    int co = o / 192;
    int kk = o - co * 192;
    int k  = kk >> 6;
    int ci = kk & 63;
    wa[o] = f2bf(w[co * 192 + ci * 3 + k]);
}

// One sample per block. 4 waves: (w&1) = co-half, (w>>1) = t-half.
// Wave (h, nh): co in [32h,32h+32) U [32h+64,32h+96) (GLU pairs in-wave),
// t in [32*nh, 32*nh+32).
__global__ __launch_bounds__(256, 2)
void conv_glu(const float* __restrict__ x, const ushort* __restrict__ wa,
              const float* __restrict__ bias, float* __restrict__ out) {
    const int n   = blockIdx.x;
    const int tid = threadIdx.x;
    const int w   = tid >> 6;      // wave id 0..3
    const int L   = tid & 63;      // lane
    const int l   = L & 15;
    const int q   = L >> 4;        // quad
    const int h   = w & 1;         // M half
    const int nh  = w >> 1;        // N half
    const int t0base = nh * 32;

    const float* xs = x + n * (CIN * TLEN);

    // A fragments (bf16 weights) — 4 M-tiles x 6 K-chunks, 16B loads, L2-hot.
    // A layout: A[m=lane&15][k=q*8+j]; row co = cobase + l, kk = kc*32 + q*8 + j.
    short8 afr[4][6];
#pragma unroll
    for (int mt = 0; mt < 4; ++mt) {
        int co = 32 * h + 16 * (mt & 1) + 64 * (mt >> 1) + l;
        const short8* wrow = (const short8*)(wa + co * 192);   // 24 short8 per row
#pragma unroll
        for (int kc = 0; kc < 6; ++kc)
            afr[mt][kc] = wrow[kc * 4 + q];
    }

    float4v acc[4][2];
#pragma unroll
    for (int mt = 0; mt < 4; ++mt)
#pragma unroll
        for (int nt = 0; nt < 2; ++nt)
            acc[mt][nt] = (float4v){0.f, 0.f, 0.f, 0.f};

    // K loop: chunk kc covers conv-tap k = kc>>1, ci base = (kc&1)*32.
    // B layout: B[k=q*8+j][n=lane&15]; element = x[ci=cib+j][t = tcol + (kc>>1)].
#pragma unroll
    for (int kc = 0; kc < 6; ++kc) {
        const int kcv = kc >> 1;
        const int cib = (kc & 1) * 32 + q * 8;
#pragma unroll
        for (int nt = 0; nt < 2; ++nt) {
            int t = t0base + nt * 16 + l + kcv;
            if (t > 63) t = 63;                   // pad cols (t>=62 results discarded)
            const float* p = xs + cib * TLEN + t;
            short8 bfr;
#pragma unroll
            for (int j = 0; j < 8; ++j)
                bfr[j] = (short)f2bf(p[j * TLEN]);   // gather stride 256B, L1-resident
#pragma unroll
            for (int mt = 0; mt < 4; ++mt)
                acc[mt][nt] = __builtin_amdgcn_mfma_f32_16x16x32_bf16(
                    afr[mt][kc], bfr, acc[mt][nt], 0, 0, 0);
        }
    }

    // Epilogue: bias + GLU. Pair (mt, mt+2) = (value co, gate co+64). fp32 store.
    // D layout: row = q*4 + r, col = l.
#pragma unroll
    for (int p2 = 0; p2 < 2; ++p2) {
#pragma unroll
        for (int nt = 0; nt < 2; ++nt) {
#pragma unroll
            for (int r = 0; r < 4; ++r) {
                int co = 32 * h + 16 * p2 + 4 * q + r;
                int t  = t0base + nt * 16 + l;
                float a = acc[p2][nt][r]     + bias[co];
                float g = acc[p2 + 2][nt][r] + bias[co + 64];
                float sg = 1.0f / (1.0f + __expf(-g));
                if (t < TOUT)
                    out[(n * COUT + co) * TOUT + t] = a * sg;
            }
        }
    }
}

extern "C" void kernel_launch(void* const* d_in, const int* in_sizes, int n_in,
                              void* d_out, int out_size, void* d_ws, size_t ws_size,
                              hipStream_t stream) {
    const float* x    = (const float*)d_in[0];
    const float* wt   = (const float*)d_in[1];
    const float* bias = (const float*)d_in[2];
    ushort*      wa   = (ushort*)d_ws;        // 48 KB permuted bf16 weights
    float*       out  = (float*)d_out;

    prep_weights<<<96, 256, 0, stream>>>(wt, wa);
    conv_glu<<<NSAMP, 256, 0, stream>>>(x, wa, bias, out);
}